// Round 18
// baseline (93.886 us; speedup 1.0000x reference)
//
#include <hip/hip_runtime.h>
#include <hip/hip_fp16.h>
#include <cstdint>
#include <cstddef>

// ---- problem constants ----
#define SEQ 2048
#define DM 1024
#define NH 16
#define NB 20

typedef _Float16 half8 __attribute__((ext_vector_type(8)));
typedef _Float16 half4 __attribute__((ext_vector_type(4)));
typedef _Float16 h2v __attribute__((ext_vector_type(2)));
typedef float f32x4 __attribute__((ext_vector_type(4)));
typedef int i32x4 __attribute__((ext_vector_type(4)));
typedef unsigned int u32;
typedef unsigned int u32x2 __attribute__((ext_vector_type(2)));

// ws layout (25,165,824 B total):
//  KF [2][16][64][2048] halves : per (b,h,kt): [k2][dh][lane][8]       (QK^T A-frags, 16x16x32)
//  VF [2][16][64][2048] halves : per (b,h,kt): [dt][lane][k2*4+r]      (PV B-frags, K=32 pi-order)
//  PB [2][64][65536] bytes     : per (b,qblk32): [kt][lane][qs][k2] u32 = pair01 | pair23<<16
//                                pair = bucket0*21+bucket1 (bucket 20 = masked sentinel)
#define KF_HALVES 4194304
#define VF_HALVES 4194304

// =================== prepass (identical to R17) ===================
__global__ __launch_bounds__(256) void pa_prep(
    const float* __restrict__ v, const float* __restrict__ k,
    const int* __restrict__ diff, const int* __restrict__ mask,
    _Float16* __restrict__ KF, _Float16* __restrict__ VF,
    unsigned char* __restrict__ PB) {
  const int bid = blockIdx.x, tid = threadIdx.x;
  if (bid < 2048) {
    int img = bid >> 4;                    // 0..127 = b*64+kt
    int bb = img >> 6, kt = img & 63;
    int tix = ((bid & 15) << 8) | tid;     // 0..4095
    int r = tix >> 7;                      // row in tile 0..31 (= k2*16+l16)
    int c0 = (tix & 127) << 3;             // col 0..1016
    const float* src = k + ((size_t)(bb * SEQ + kt * 32 + r)) * DM + c0;
    f32x4 a = *(const f32x4*)src;
    f32x4 c = *(const f32x4*)(src + 4);
    half8 o = {(_Float16)a[0], (_Float16)a[1], (_Float16)a[2], (_Float16)a[3],
               (_Float16)c[0], (_Float16)c[1], (_Float16)c[2], (_Float16)c[3]};
    int h = c0 >> 6, dh = (c0 >> 5) & 1, g4 = (c0 >> 3) & 3;
    int k2 = r >> 4, l16 = r & 15;
    int lane = g4 * 16 + l16;
    size_t off = ((size_t)((bb * 16 + h) * 64 + kt)) * 2048 + (k2 * 2 + dh) * 512 + lane * 8;
    *(half8*)(KF + off) = o;
  } else if (bid < 3072) {
    int b3 = bid - 2048;
    int img = b3 >> 3;                     // 0..127
    int bb = img >> 6, kt = img & 63;
    int tix = ((b3 & 7) << 8) | tid;       // 0..2047
    int kq = tix >> 8;                     // 0..7
    int k2 = kq >> 2, g4 = kq & 3;
    int d0 = (tix & 255) << 2;             // 0..1020
    const float* src = v + ((size_t)(bb * SEQ + kt * 32 + k2 * 16 + g4 * 4)) * DM + d0;
    f32x4 m0 = *(const f32x4*)(src);
    f32x4 m1 = *(const f32x4*)(src + DM);
    f32x4 m2 = *(const f32x4*)(src + 2 * DM);
    f32x4 m3 = *(const f32x4*)(src + 3 * DM);
#pragma unroll
    for (int i = 0; i < 4; ++i) {
      int d = d0 + i;
      int l16 = d & 15, dt = (d >> 4) & 3, h = d >> 6;
      int lane = g4 * 16 + l16;
      half4 o = {(_Float16)m0[i], (_Float16)m1[i], (_Float16)m2[i], (_Float16)m3[i]};
      size_t off = ((size_t)((bb * 16 + h) * 64 + kt)) * 2048 + dt * 512 + lane * 8 + k2 * 4;
      *(half4*)(VF + off) = o;
    }
  } else {
    int b4 = bid - 3072;                   // 0..4095
    int job = b4 >> 5;                     // 0..127 = b*64+qblk32
    int bb = job >> 6, qblk = job & 63;
    int tix = ((b4 & 31) << 8) | tid;      // 0..8191
    int kt = tix >> 7;
    int rem = tix & 127;
    int g4 = rem & 3, l16 = (rem >> 2) & 15, qs = rem >> 6;
    int lane = g4 * 16 + l16;
    int qrow = qblk * 32 + qs * 16 + l16;
    size_t rowbase = ((size_t)(bb * SEQ + qrow)) * SEQ;
    u32x2 wds;
#pragma unroll
    for (int k2 = 0; k2 < 2; ++k2) {
      int kk = kt * 32 + k2 * 16 + g4 * 4;
      i32x4 dv = *(const i32x4*)(diff + rowbase + kk);
      i32x4 mv = *(const i32x4*)(mask + rowbase + kk);
      u32 bk[4];
#pragma unroll
      for (int r = 0; r < 4; ++r) bk[r] = mv[r] ? (u32)dv[r] : 20u;  // 20 = masked sentinel
      u32 pi01 = bk[0] * 21 + bk[1];
      u32 pi23 = bk[2] * 21 + bk[3];
      wds[k2] = pi01 | (pi23 << 16);
    }
    size_t off = ((size_t)job) * 65536 + (size_t)kt * 1024 + (size_t)lane * 16 + (size_t)qs * 8;
    *(u32x2*)(PB + off) = wds;
  }
}

__device__ __forceinline__ void gll16(const _Float16* g, _Float16* l) {
  __builtin_amdgcn_global_load_lds(
      (const __attribute__((address_space(1))) unsigned int*)g,
      (__attribute__((address_space(3))) unsigned int*)l, 16, 0, 0);
}

// packed-f16 silu with f16 bias pairs; masked bias ~ -3e4 -> exp2(+4.3e4)=inf -> y=0 exactly
__device__ __forceinline__ half4 silu4b(const f32x4& s, h2v b01, h2v b23) {
  h2v x01 = __builtin_bit_cast(h2v, __builtin_amdgcn_cvt_pkrtz(s[0], s[1])) + b01;
  h2v x23 = __builtin_bit_cast(h2v, __builtin_amdgcn_cvt_pkrtz(s[2], s[3])) + b23;
  const h2v NL2E = {(_Float16)-1.44269504f, (_Float16)-1.44269504f};
  const h2v ONE = {(_Float16)1.0f, (_Float16)1.0f};
  h2v m01 = x01 * NL2E, m23 = x23 * NL2E;
  h2v e01 = __builtin_bit_cast(h2v, h2exp2(__builtin_bit_cast(__half2, m01)));
  h2v e23 = __builtin_bit_cast(h2v, h2exp2(__builtin_bit_cast(__half2, m23)));
  h2v d01 = e01 + ONE, d23 = e23 + ONE;
  h2v y01 = x01 * __builtin_bit_cast(h2v, h2rcp(__builtin_bit_cast(__half2, d01)));
  h2v y23 = x23 * __builtin_bit_cast(h2v, h2rcp(__builtin_bit_cast(__half2, d23)));
  return (half4){y01[0], y01[1], y23[0], y23[1]};
}

struct BiasSet { h2v b[2][2][2]; };  // [qs][k2][pair01/pair23], f16

// =================== main: f16 pair table + 4-slot ring (1 barrier / 2 tiles) ===================
// R17 (-10us) validated the sum-of-pipes model: keep cutting ops. This round:
// (1) table entries = packed f16 pairs -> gathers are ds_read_b32 (half the bank touches),
//     bias re-joins silu as f16 pk-add (QK C-op freed, MFMAs independent of gather);
// (2) 4-slot LDS ring staging 2 tiles per __syncthreads() -> 32 barriers instead of 64.
__global__ __launch_bounds__(256, 4) void pa_main(
    const _Float16* __restrict__ KF, const _Float16* __restrict__ VF,
    const unsigned char* __restrict__ PB, const float* __restrict__ q,
    const float* __restrict__ relbias, float* __restrict__ out) {
  __shared__ _Float16 ring[4][4096];   // slot: K halves [0..2047] | V halves [2048..4095]
  __shared__ u32 tabH[441];            // packed (f16,f16) bias pairs; index i*21+j

  const int tid = threadIdx.x, lane = tid & 63, wid = tid >> 6;
  const int l16 = lane & 15, g4 = lane >> 4;
  const int xcd = blockIdx.x & 7;        // bid%8 = XCD
  const int i = blockIdx.x >> 3;         // 0..63 within XCD
  const int b = xcd >> 2;                // XCD owns (b, 4-head group)
  const int hg = xcd & 3;
  const int h = hg * 4 + (i & 3);
  const int qgrp = i >> 2;               // 0..15
  const int qblk = qgrp * 4 + wid;
  const int qbase = qblk * 32;

  // build f16 pair table (441 entries)
  for (int e = tid; e < 441; e += 256) {
    int bi = e / 21, bj = e - bi * 21;
    float vi = (bi < NB) ? relbias[bi * NH + h] : -30000.0f;
    float vj = (bj < NB) ? relbias[bj * NH + h] : -30000.0f;
    tabH[e] = __builtin_bit_cast(u32, __builtin_amdgcn_cvt_pkrtz(vi, vj));
  }

  half8 qf[2][2];
#pragma unroll
  for (int qs = 0; qs < 2; ++qs)
#pragma unroll
    for (int dh = 0; dh < 2; ++dh) {
      const float* s = q + ((size_t)(b * SEQ + qbase + qs * 16 + l16)) * DM + h * 64 + dh * 32 + g4 * 8;
      f32x4 a = *(const f32x4*)s;
      f32x4 c = *(const f32x4*)(s + 4);
      qf[qs][dh] = {(_Float16)(a[0] * 0.125f), (_Float16)(a[1] * 0.125f),
                    (_Float16)(a[2] * 0.125f), (_Float16)(a[3] * 0.125f),
                    (_Float16)(c[0] * 0.125f), (_Float16)(c[1] * 0.125f),
                    (_Float16)(c[2] * 0.125f), (_Float16)(c[3] * 0.125f)};
    }

  f32x4 acc[2][4];
#pragma unroll
  for (int qs = 0; qs < 2; ++qs)
#pragma unroll
    for (int dt = 0; dt < 4; ++dt) acc[qs][dt] = (f32x4){0.f, 0.f, 0.f, 0.f};

  const _Float16* kfb = KF + ((size_t)((b * 16 + h) * 64)) * 2048 + lane * 8;
  const _Float16* vfb = VF + ((size_t)((b * 16 + h) * 64)) * 2048 + lane * 8;
  const unsigned char* pbb = PB + ((size_t)(b * 64 + qblk)) * 65536 + lane * 16;
  const int c512 = wid * 512;

#define STAGE(T)                                                            \
  do {                                                                      \
    int sl_ = (T) & 3;                                                      \
    gll16(kfb + (size_t)(T) * 2048 + c512, &ring[sl_][c512]);               \
    gll16(vfb + (size_t)(T) * 2048 + c512, &ring[sl_][2048 + c512]);        \
  } while (0)
#define CLMP(T) ((T) < 64 ? (T) : 63)

#define GATHER(BS, PQ)                                                      \
  do {                                                                      \
    _Pragma("unroll") for (int qs = 0; qs < 2; ++qs)                        \
      _Pragma("unroll") for (int k2 = 0; k2 < 2; ++k2) {                    \
        u32 w = (u32)PQ[qs * 2 + k2];                                       \
        BS.b[qs][k2][0] = __builtin_bit_cast(h2v, tabH[w & 0xffffu]);       \
        BS.b[qs][k2][1] = __builtin_bit_cast(h2v, tabH[w >> 16]);           \
      }                                                                     \
  } while (0)

#define COMPUTE(SL, BS)                                                                      \
  do {                                                                                       \
    const f32x4 zf = {0.f, 0.f, 0.f, 0.f};                                                   \
    half8 kfr[4], vvr[4];                                                                    \
    _Pragma("unroll") for (int j = 0; j < 4; ++j) {                                          \
      kfr[j] = *(const half8*)&ring[SL][j * 512 + lane * 8];                                 \
      vvr[j] = *(const half8*)&ring[SL][2048 + j * 512 + lane * 8];                          \
    }                                                                                        \
    f32x4 sa[2][2];                                                                          \
    _Pragma("unroll") for (int qs = 0; qs < 2; ++qs)                                         \
      _Pragma("unroll") for (int k2 = 0; k2 < 2; ++k2) {                                     \
        sa[qs][k2] = __builtin_amdgcn_mfma_f32_16x16x32_f16(kfr[k2 * 2 + 0], qf[qs][0],      \
                                                            zf, 0, 0, 0);                    \
        sa[qs][k2] = __builtin_amdgcn_mfma_f32_16x16x32_f16(kfr[k2 * 2 + 1], qf[qs][1],      \
                                                            sa[qs][k2], 0, 0, 0);            \
      }                                                                                      \
    half8 pf8[2];                                                                            \
    _Pragma("unroll") for (int qs = 0; qs < 2; ++qs) {                                       \
      half4 p0 = silu4b(sa[qs][0], BS.b[qs][0][0], BS.b[qs][0][1]);                          \
      half4 p1 = silu4b(sa[qs][1], BS.b[qs][1][0], BS.b[qs][1][1]);                          \
      pf8[qs] = (half8){p0[0], p0[1], p0[2], p0[3], p1[0], p1[1], p1[2], p1[3]};             \
    }                                                                                        \
    _Pragma("unroll") for (int qs = 0; qs < 2; ++qs)                                         \
      _Pragma("unroll") for (int dt = 0; dt < 4; ++dt)                                       \
        acc[qs][dt] = __builtin_amdgcn_mfma_f32_16x16x32_f16(pf8[qs], vvr[dt],               \
                                                             acc[qs][dt], 0, 0, 0);          \
  } while (0)

  BiasSet bE, bO;
  i32x4 pqE, pqO, pqE2, pqO2;

  // prologue: stage tiles 0,1 into slots 0,1; pq(0),pq(1) in regs; table published
  STAGE(0);
  STAGE(1);
  pqE = *(const i32x4*)(pbb);
  pqO = *(const i32x4*)(pbb + 1024);
  __syncthreads();                       // drains stages 0,1; table visible

  for (int t = 0; t < 64; t += 2) {
    // stage t+2,t+3 (overwrites slots of t-2,t-1 — reads finished before previous barrier)
    STAGE(CLMP(t + 2));
    STAGE(CLMP(t + 3));
    pqE2 = *(const i32x4*)(pbb + (size_t)CLMP(t + 2) * 1024);
    pqO2 = *(const i32x4*)(pbb + (size_t)CLMP(t + 3) * 1024);
    __builtin_amdgcn_sched_barrier(0);
    GATHER(bE, pqE);                     // bias t (hides under QK MFMAs)
    GATHER(bO, pqO);                     // bias t+1 (hides under compute t)
    COMPUTE(t & 3, bE);
    COMPUTE((t + 1) & 3, bO);
    __syncthreads();                     // stages t+2,t+3 complete; slots t,t+1 released
    pqE = pqE2;
    pqO = pqO2;
  }
#undef STAGE
#undef CLMP
#undef GATHER
#undef COMPUTE

  // epilogue: full-k accumulators -> direct stores (no memset, no atomics)
#pragma unroll
  for (int qs = 0; qs < 2; ++qs)
#pragma unroll
    for (int dt = 0; dt < 4; ++dt)
#pragma unroll
      for (int r = 0; r < 4; ++r) {
        int qrow = qbase + qs * 16 + g4 * 4 + r;
        int d = h * 64 + dt * 16 + l16;
        out[((size_t)(b * SEQ) + qrow) * DM + d] = acc[qs][dt][r];
      }
}

extern "C" void kernel_launch(void* const* d_in, const int* in_sizes, int n_in,
                              void* d_out, int out_size, void* d_ws, size_t ws_size,
                              hipStream_t stream) {
  const float* v = (const float*)d_in[0];
  const float* k = (const float*)d_in[1];
  const float* q = (const float*)d_in[2];
  const int* mask = (const int*)d_in[3];
  const int* diff = (const int*)d_in[4];
  const float* relbias = (const float*)d_in[5];
  float* out = (float*)d_out;

  _Float16* KF = (_Float16*)d_ws;
  _Float16* VF = KF + KF_HALVES;
  unsigned char* PB = (unsigned char*)(VF + VF_HALVES);
  if (ws_size < (size_t)25165824) return;

  pa_prep<<<7168, 256, 0, stream>>>(v, k, diff, mask, KF, VF, PB);
  pa_main<<<512, 256, 0, stream>>>(KF, VF, PB, q, relbias, out);
}

// Round 19
// 91.348 us; speedup vs baseline: 1.0278x; 1.0278x over previous
//
#include <hip/hip_runtime.h>
#include <hip/hip_fp16.h>
#include <cstdint>
#include <cstddef>

// ---- problem constants ----
#define SEQ 2048
#define DM 1024
#define NH 16
#define NB 20

typedef _Float16 half8 __attribute__((ext_vector_type(8)));
typedef _Float16 half4 __attribute__((ext_vector_type(4)));
typedef _Float16 h2v __attribute__((ext_vector_type(2)));
typedef float f32x4 __attribute__((ext_vector_type(4)));
typedef float f32x2 __attribute__((ext_vector_type(2)));
typedef int i32x4 __attribute__((ext_vector_type(4)));
typedef unsigned int u32;
typedef unsigned int u32x2 __attribute__((ext_vector_type(2)));

// ws layout (25,165,824 B total):
//  KF [2][16][64][2048] halves : per (b,h,kt): [k2][dh][lane][8]       (QK^T A-frags, 16x16x32)
//  VF [2][16][64][2048] halves : per (b,h,kt): [dt][lane][k2*4+r]      (PV B-frags, K=32 pi-order)
//  PB [2][64][65536] bytes     : per (b,qblk32): [kt][lane][qs][k2] u32 = pair01 | pair23<<16
//                                pair = bucket0*21+bucket1 (bucket 20 = masked sentinel)
#define KF_HALVES 4194304
#define VF_HALVES 4194304

// =================== prepass (identical to R17) ===================
__global__ __launch_bounds__(256) void pa_prep(
    const float* __restrict__ v, const float* __restrict__ k,
    const int* __restrict__ diff, const int* __restrict__ mask,
    _Float16* __restrict__ KF, _Float16* __restrict__ VF,
    unsigned char* __restrict__ PB) {
  const int bid = blockIdx.x, tid = threadIdx.x;
  if (bid < 2048) {
    int img = bid >> 4;                    // 0..127 = b*64+kt
    int bb = img >> 6, kt = img & 63;
    int tix = ((bid & 15) << 8) | tid;     // 0..4095
    int r = tix >> 7;                      // row in tile 0..31 (= k2*16+l16)
    int c0 = (tix & 127) << 3;             // col 0..1016
    const float* src = k + ((size_t)(bb * SEQ + kt * 32 + r)) * DM + c0;
    f32x4 a = *(const f32x4*)src;
    f32x4 c = *(const f32x4*)(src + 4);
    half8 o = {(_Float16)a[0], (_Float16)a[1], (_Float16)a[2], (_Float16)a[3],
               (_Float16)c[0], (_Float16)c[1], (_Float16)c[2], (_Float16)c[3]};
    int h = c0 >> 6, dh = (c0 >> 5) & 1, g4 = (c0 >> 3) & 3;
    int k2 = r >> 4, l16 = r & 15;
    int lane = g4 * 16 + l16;
    size_t off = ((size_t)((bb * 16 + h) * 64 + kt)) * 2048 + (k2 * 2 + dh) * 512 + lane * 8;
    *(half8*)(KF + off) = o;
  } else if (bid < 3072) {
    int b3 = bid - 2048;
    int img = b3 >> 3;                     // 0..127
    int bb = img >> 6, kt = img & 63;
    int tix = ((b3 & 7) << 8) | tid;       // 0..2047
    int kq = tix >> 8;                     // 0..7
    int k2 = kq >> 2, g4 = kq & 3;
    int d0 = (tix & 255) << 2;             // 0..1020
    const float* src = v + ((size_t)(bb * SEQ + kt * 32 + k2 * 16 + g4 * 4)) * DM + d0;
    f32x4 m0 = *(const f32x4*)(src);
    f32x4 m1 = *(const f32x4*)(src + DM);
    f32x4 m2 = *(const f32x4*)(src + 2 * DM);
    f32x4 m3 = *(const f32x4*)(src + 3 * DM);
#pragma unroll
    for (int i = 0; i < 4; ++i) {
      int d = d0 + i;
      int l16 = d & 15, dt = (d >> 4) & 3, h = d >> 6;
      int lane = g4 * 16 + l16;
      half4 o = {(_Float16)m0[i], (_Float16)m1[i], (_Float16)m2[i], (_Float16)m3[i]};
      size_t off = ((size_t)((bb * 16 + h) * 64 + kt)) * 2048 + dt * 512 + lane * 8 + k2 * 4;
      *(half4*)(VF + off) = o;
    }
  } else {
    int b4 = bid - 3072;                   // 0..4095
    int job = b4 >> 5;                     // 0..127 = b*64+qblk32
    int bb = job >> 6, qblk = job & 63;
    int tix = ((b4 & 31) << 8) | tid;      // 0..8191
    int kt = tix >> 7;
    int rem = tix & 127;
    int g4 = rem & 3, l16 = (rem >> 2) & 15, qs = rem >> 6;
    int lane = g4 * 16 + l16;
    int qrow = qblk * 32 + qs * 16 + l16;
    size_t rowbase = ((size_t)(bb * SEQ + qrow)) * SEQ;
    u32x2 wds;
#pragma unroll
    for (int k2 = 0; k2 < 2; ++k2) {
      int kk = kt * 32 + k2 * 16 + g4 * 4;
      i32x4 dv = *(const i32x4*)(diff + rowbase + kk);
      i32x4 mv = *(const i32x4*)(mask + rowbase + kk);
      u32 bk[4];
#pragma unroll
      for (int r = 0; r < 4; ++r) bk[r] = mv[r] ? (u32)dv[r] : 20u;  // 20 = masked sentinel
      u32 pi01 = bk[0] * 21 + bk[1];
      u32 pi23 = bk[2] * 21 + bk[3];
      wds[k2] = pi01 | (pi23 << 16);
    }
    size_t off = ((size_t)job) * 65536 + (size_t)kt * 1024 + (size_t)lane * 16 + (size_t)qs * 8;
    *(u32x2*)(PB + off) = wds;
  }
}

__device__ __forceinline__ void gll16(const _Float16* g, _Float16* l) {
  __builtin_amdgcn_global_load_lds(
      (const __attribute__((address_space(1))) unsigned int*)g,
      (__attribute__((address_space(3))) unsigned int*)l, 16, 0, 0);
}

// packed-f16 silu; bias already in s (came through the MFMA C-operand in f32)
__device__ __forceinline__ half4 silu4nb(const f32x4& s) {
  h2v x01 = __builtin_bit_cast(h2v, __builtin_amdgcn_cvt_pkrtz(s[0], s[1]));
  h2v x23 = __builtin_bit_cast(h2v, __builtin_amdgcn_cvt_pkrtz(s[2], s[3]));
  const h2v NL2E = {(_Float16)-1.44269504f, (_Float16)-1.44269504f};
  const h2v ONE = {(_Float16)1.0f, (_Float16)1.0f};
  h2v m01 = x01 * NL2E, m23 = x23 * NL2E;
  h2v e01 = __builtin_bit_cast(h2v, h2exp2(__builtin_bit_cast(__half2, m01)));
  h2v e23 = __builtin_bit_cast(h2v, h2exp2(__builtin_bit_cast(__half2, m23)));
  h2v d01 = e01 + ONE, d23 = e23 + ONE;
  h2v y01 = x01 * __builtin_bit_cast(h2v, h2rcp(__builtin_bit_cast(__half2, d01)));
  h2v y23 = x23 * __builtin_bit_cast(h2v, h2rcp(__builtin_bit_cast(__half2, d23)));
  return (half4){y01[0], y01[1], y23[0], y23[1]};
}

struct BiasSet { f32x4 b[2][2]; };  // [qs][k2], f32 — feeds QK C-operand

// =================== main: pipe-balanced (K via LDS ring, V via VMEM regs) ===================
// R17/R18 counters close the model: LDS pipe ~94% saturated (K+V fragment reads + gathers
// all on one per-CU LDS unit). Balance the two pipes: K stays LDS-staged (gll16 ring),
// V fragments load per-wave DIRECT from VMEM (4 waves identical addrs -> L1-served),
// cutting LDS demand ~1/3. Everything else = R17 exactly (best: 72.5us main).
__global__ __launch_bounds__(256, 4) void pa_main(
    const _Float16* __restrict__ KF, const _Float16* __restrict__ VF,
    const unsigned char* __restrict__ PB, const float* __restrict__ q,
    const float* __restrict__ relbias, float* __restrict__ out) {
  __shared__ _Float16 ringK[2][2048];  // K tile double-buffer (8KB)
  __shared__ f32x2 tabF[441];          // (rb[i], rb[j]) pair table; rb[20] = -3e4

  const int tid = threadIdx.x, lane = tid & 63, wid = tid >> 6;
  const int l16 = lane & 15, g4 = lane >> 4;
  const int xcd = blockIdx.x & 7;        // bid%8 = XCD
  const int i = blockIdx.x >> 3;         // 0..63 within XCD
  const int b = xcd >> 2;                // XCD owns (b, 4-head group)
  const int hg = xcd & 3;
  const int h = hg * 4 + (i & 3);
  const int qgrp = i >> 2;               // 0..15
  const int qblk = qgrp * 4 + wid;
  const int qbase = qblk * 32;

  // build pair table (441 entries)
  for (int e = tid; e < 441; e += 256) {
    int bi = e / 21, bj = e - bi * 21;
    float vi = (bi < NB) ? relbias[bi * NH + h] : -30000.0f;
    float vj = (bj < NB) ? relbias[bj * NH + h] : -30000.0f;
    tabF[e] = (f32x2){vi, vj};
  }

  half8 qf[2][2];
#pragma unroll
  for (int qs = 0; qs < 2; ++qs)
#pragma unroll
    for (int dh = 0; dh < 2; ++dh) {
      const float* s = q + ((size_t)(b * SEQ + qbase + qs * 16 + l16)) * DM + h * 64 + dh * 32 + g4 * 8;
      f32x4 a = *(const f32x4*)s;
      f32x4 c = *(const f32x4*)(s + 4);
      qf[qs][dh] = {(_Float16)(a[0] * 0.125f), (_Float16)(a[1] * 0.125f),
                    (_Float16)(a[2] * 0.125f), (_Float16)(a[3] * 0.125f),
                    (_Float16)(c[0] * 0.125f), (_Float16)(c[1] * 0.125f),
                    (_Float16)(c[2] * 0.125f), (_Float16)(c[3] * 0.125f)};
    }

  f32x4 acc[2][4];
#pragma unroll
  for (int qs = 0; qs < 2; ++qs)
#pragma unroll
    for (int dt = 0; dt < 4; ++dt) acc[qs][dt] = (f32x4){0.f, 0.f, 0.f, 0.f};

  const _Float16* kfb = KF + ((size_t)((b * 16 + h) * 64)) * 2048 + lane * 8;
  const _Float16* vfb = VF + ((size_t)((b * 16 + h) * 64)) * 2048 + lane * 8;
  const unsigned char* pbb = PB + ((size_t)(b * 64 + qblk)) * 65536 + lane * 16;
  const int c512 = wid * 512;

#define STAGE(T, B) gll16(kfb + (size_t)(T) * 2048 + c512, &ringK[B][c512])
#define CLMP(T) ((T) < 64 ? (T) : 63)

#define GATHER(BS, PQ)                                                 \
  do {                                                                 \
    _Pragma("unroll") for (int qs = 0; qs < 2; ++qs)                   \
      _Pragma("unroll") for (int k2 = 0; k2 < 2; ++k2) {               \
        u32 w = (u32)PQ[qs * 2 + k2];                                  \
        f32x2 p01 = tabF[w & 0xffffu];                                 \
        f32x2 p23 = tabF[w >> 16];                                     \
        BS.b[qs][k2] = (f32x4){p01[0], p01[1], p23[0], p23[1]};        \
      }                                                                \
  } while (0)

#define COMPUTE(B, BS, T)                                                                    \
  do {                                                                                       \
    half8 vvr[4];                                                                            \
    _Pragma("unroll") for (int j = 0; j < 4; ++j)                                            \
      vvr[j] = *(const half8*)(vfb + (size_t)(T) * 2048 + j * 512);   /* VMEM: L1-shared */  \
    half8 kfr[4];                                                                            \
    _Pragma("unroll") for (int j = 0; j < 4; ++j)                                            \
      kfr[j] = *(const half8*)&ringK[B][j * 512 + lane * 8];          /* LDS pipe */         \
    f32x4 sa[2][2];                                                                          \
    _Pragma("unroll") for (int qs = 0; qs < 2; ++qs)                                         \
      _Pragma("unroll") for (int k2 = 0; k2 < 2; ++k2) {                                     \
        sa[qs][k2] = __builtin_amdgcn_mfma_f32_16x16x32_f16(kfr[k2 * 2 + 0], qf[qs][0],      \
                                                            BS.b[qs][k2], 0, 0, 0);          \
        sa[qs][k2] = __builtin_amdgcn_mfma_f32_16x16x32_f16(kfr[k2 * 2 + 1], qf[qs][1],      \
                                                            sa[qs][k2], 0, 0, 0);            \
      }                                                                                      \
    half8 pf8[2];                                                                            \
    _Pragma("unroll") for (int qs = 0; qs < 2; ++qs) {                                       \
      half4 p0 = silu4nb(sa[qs][0]);                                                         \
      half4 p1 = silu4nb(sa[qs][1]);                                                         \
      pf8[qs] = (half8){p0[0], p0[1], p0[2], p0[3], p1[0], p1[1], p1[2], p1[3]};             \
    }                                                                                        \
    _Pragma("unroll") for (int qs = 0; qs < 2; ++qs)                                         \
      _Pragma("unroll") for (int dt = 0; dt < 4; ++dt)                                       \
        acc[qs][dt] = __builtin_amdgcn_mfma_f32_16x16x32_f16(pf8[qs], vvr[dt],               \
                                                             acc[qs][dt], 0, 0, 0);          \
  } while (0)

  BiasSet biasA, biasB;
  i32x4 pq1, pqX;

  // prologue: stage K tile0 -> buf0; table built; bias(0); pq(1) in flight
  STAGE(0, 0);
  i32x4 pq0 = *(const i32x4*)(pbb);
  pq1 = *(const i32x4*)(pbb + 1024);
  __syncthreads();                      // drains stage(0), publishes table
  GATHER(biasA, pq0);

  for (int t = 0; t < 64; t += 2) {
    // even phase: stage K(t+1) -> buf1; compute t from buf0 (V direct from VMEM)
    STAGE(t + 1, 1);
    pqX = *(const i32x4*)(pbb + (size_t)CLMP(t + 2) * 1024);
    __builtin_amdgcn_sched_barrier(0);
    GATHER(biasB, pq1);                 // bias for t+1, hides under compute t
    COMPUTE(0, biasA, t);
    __syncthreads();                    // buf1 ready; all waves done with buf0
    // odd phase: stage K(t+2) -> buf0; compute t+1 from buf1
    STAGE(CLMP(t + 2), 0);
    pq1 = *(const i32x4*)(pbb + (size_t)CLMP(t + 3) * 1024);
    __builtin_amdgcn_sched_barrier(0);
    GATHER(biasA, pqX);                 // bias for t+2
    COMPUTE(1, biasB, t + 1);
    __syncthreads();
  }
#undef STAGE
#undef CLMP
#undef GATHER
#undef COMPUTE

  // epilogue: full-k accumulators -> direct stores (no memset, no atomics)
#pragma unroll
  for (int qs = 0; qs < 2; ++qs)
#pragma unroll
    for (int dt = 0; dt < 4; ++dt)
#pragma unroll
      for (int r = 0; r < 4; ++r) {
        int qrow = qbase + qs * 16 + g4 * 4 + r;
        int d = h * 64 + dt * 16 + l16;
        out[((size_t)(b * SEQ) + qrow) * DM + d] = acc[qs][dt][r];
      }
}

extern "C" void kernel_launch(void* const* d_in, const int* in_sizes, int n_in,
                              void* d_out, int out_size, void* d_ws, size_t ws_size,
                              hipStream_t stream) {
  const float* v = (const float*)d_in[0];
  const float* k = (const float*)d_in[1];
  const float* q = (const float*)d_in[2];
  const int* mask = (const int*)d_in[3];
  const int* diff = (const int*)d_in[4];
  const float* relbias = (const float*)d_in[5];
  float* out = (float*)d_out;

  _Float16* KF = (_Float16*)d_ws;
  _Float16* VF = KF + KF_HALVES;
  unsigned char* PB = (unsigned char*)(VF + VF_HALVES);
  if (ws_size < (size_t)25165824) return;

  pa_prep<<<7168, 256, 0, stream>>>(v, k, diff, mask, KF, VF, PB);
  pa_main<<<512, 256, 0, stream>>>(KF, VF, PB, q, relbias, out);
}

// Round 20
// 87.478 us; speedup vs baseline: 1.0732x; 1.0442x over previous
//
#include <hip/hip_runtime.h>
#include <hip/hip_fp16.h>
#include <cstdint>
#include <cstddef>

// ---- problem constants ----
#define SEQ 2048
#define DM 1024
#define NH 16
#define NB 20

typedef _Float16 half8 __attribute__((ext_vector_type(8)));
typedef _Float16 half4 __attribute__((ext_vector_type(4)));
typedef _Float16 h2v __attribute__((ext_vector_type(2)));
typedef float f32x4 __attribute__((ext_vector_type(4)));
typedef float f32x2 __attribute__((ext_vector_type(2)));
typedef int i32x4 __attribute__((ext_vector_type(4)));
typedef unsigned int u32;
typedef unsigned int u32x2 __attribute__((ext_vector_type(2)));

// ws layout (25,165,824 B total):
//  KF [2][16][64][2048] halves : per (b,h,kt): [k2][dh][lane][8]       (QK^T A-frags, 16x16x32)
//  VF [2][16][64][2048] halves : per (b,h,kt): [dt][lane][k2*4+r]      (PV B-frags, K=32 pi-order)
//  PB [2][64][65536] bytes     : per (b,qblk32): [kt][lane][qs][k2] u32 = pair01 | pair23<<16
//                                pair = bucket0*21+bucket1 (bucket 20 = masked sentinel)
#define KF_HALVES 4194304
#define VF_HALVES 4194304

// =================== prepass (identical to R17) ===================
__global__ __launch_bounds__(256) void pa_prep(
    const float* __restrict__ v, const float* __restrict__ k,
    const int* __restrict__ diff, const int* __restrict__ mask,
    _Float16* __restrict__ KF, _Float16* __restrict__ VF,
    unsigned char* __restrict__ PB) {
  const int bid = blockIdx.x, tid = threadIdx.x;
  if (bid < 2048) {
    int img = bid >> 4;                    // 0..127 = b*64+kt
    int bb = img >> 6, kt = img & 63;
    int tix = ((bid & 15) << 8) | tid;     // 0..4095
    int r = tix >> 7;                      // row in tile 0..31 (= k2*16+l16)
    int c0 = (tix & 127) << 3;             // col 0..1016
    const float* src = k + ((size_t)(bb * SEQ + kt * 32 + r)) * DM + c0;
    f32x4 a = *(const f32x4*)src;
    f32x4 c = *(const f32x4*)(src + 4);
    half8 o = {(_Float16)a[0], (_Float16)a[1], (_Float16)a[2], (_Float16)a[3],
               (_Float16)c[0], (_Float16)c[1], (_Float16)c[2], (_Float16)c[3]};
    int h = c0 >> 6, dh = (c0 >> 5) & 1, g4 = (c0 >> 3) & 3;
    int k2 = r >> 4, l16 = r & 15;
    int lane = g4 * 16 + l16;
    size_t off = ((size_t)((bb * 16 + h) * 64 + kt)) * 2048 + (k2 * 2 + dh) * 512 + lane * 8;
    *(half8*)(KF + off) = o;
  } else if (bid < 3072) {
    int b3 = bid - 2048;
    int img = b3 >> 3;                     // 0..127
    int bb = img >> 6, kt = img & 63;
    int tix = ((b3 & 7) << 8) | tid;       // 0..2047
    int kq = tix >> 8;                     // 0..7
    int k2 = kq >> 2, g4 = kq & 3;
    int d0 = (tix & 255) << 2;             // 0..1020
    const float* src = v + ((size_t)(bb * SEQ + kt * 32 + k2 * 16 + g4 * 4)) * DM + d0;
    f32x4 m0 = *(const f32x4*)(src);
    f32x4 m1 = *(const f32x4*)(src + DM);
    f32x4 m2 = *(const f32x4*)(src + 2 * DM);
    f32x4 m3 = *(const f32x4*)(src + 3 * DM);
#pragma unroll
    for (int i = 0; i < 4; ++i) {
      int d = d0 + i;
      int l16 = d & 15, dt = (d >> 4) & 3, h = d >> 6;
      int lane = g4 * 16 + l16;
      half4 o = {(_Float16)m0[i], (_Float16)m1[i], (_Float16)m2[i], (_Float16)m3[i]};
      size_t off = ((size_t)((bb * 16 + h) * 64 + kt)) * 2048 + dt * 512 + lane * 8 + k2 * 4;
      *(half4*)(VF + off) = o;
    }
  } else {
    int b4 = bid - 3072;                   // 0..4095
    int job = b4 >> 5;                     // 0..127 = b*64+qblk32
    int bb = job >> 6, qblk = job & 63;
    int tix = ((b4 & 31) << 8) | tid;      // 0..8191
    int kt = tix >> 7;
    int rem = tix & 127;
    int g4 = rem & 3, l16 = (rem >> 2) & 15, qs = rem >> 6;
    int lane = g4 * 16 + l16;
    int qrow = qblk * 32 + qs * 16 + l16;
    size_t rowbase = ((size_t)(bb * SEQ + qrow)) * SEQ;
    u32x2 wds;
#pragma unroll
    for (int k2 = 0; k2 < 2; ++k2) {
      int kk = kt * 32 + k2 * 16 + g4 * 4;
      i32x4 dv = *(const i32x4*)(diff + rowbase + kk);
      i32x4 mv = *(const i32x4*)(mask + rowbase + kk);
      u32 bk[4];
#pragma unroll
      for (int r = 0; r < 4; ++r) bk[r] = mv[r] ? (u32)dv[r] : 20u;  // 20 = masked sentinel
      u32 pi01 = bk[0] * 21 + bk[1];
      u32 pi23 = bk[2] * 21 + bk[3];
      wds[k2] = pi01 | (pi23 << 16);
    }
    size_t off = ((size_t)job) * 65536 + (size_t)kt * 1024 + (size_t)lane * 16 + (size_t)qs * 8;
    *(u32x2*)(PB + off) = wds;
  }
}

__device__ __forceinline__ void gll16(const _Float16* g, _Float16* l) {
  __builtin_amdgcn_global_load_lds(
      (const __attribute__((address_space(1))) unsigned int*)g,
      (__attribute__((address_space(3))) unsigned int*)l, 16, 0, 0);
}

// packed-f16 silu; bias already in s (came through the MFMA C-operand in f32)
__device__ __forceinline__ half4 silu4nb(const f32x4& s) {
  h2v x01 = __builtin_bit_cast(h2v, __builtin_amdgcn_cvt_pkrtz(s[0], s[1]));
  h2v x23 = __builtin_bit_cast(h2v, __builtin_amdgcn_cvt_pkrtz(s[2], s[3]));
  const h2v NL2E = {(_Float16)-1.44269504f, (_Float16)-1.44269504f};
  const h2v ONE = {(_Float16)1.0f, (_Float16)1.0f};
  h2v m01 = x01 * NL2E, m23 = x23 * NL2E;
  h2v e01 = __builtin_bit_cast(h2v, h2exp2(__builtin_bit_cast(__half2, m01)));
  h2v e23 = __builtin_bit_cast(h2v, h2exp2(__builtin_bit_cast(__half2, m23)));
  h2v d01 = e01 + ONE, d23 = e23 + ONE;
  h2v y01 = x01 * __builtin_bit_cast(h2v, h2rcp(__builtin_bit_cast(__half2, d01)));
  h2v y23 = x23 * __builtin_bit_cast(h2v, h2rcp(__builtin_bit_cast(__half2, d23)));
  return (half4){y01[0], y01[1], y23[0], y23[1]};
}

struct BiasSet { f32x4 b[2][2]; };  // [qs][k2], f32 — feeds QK C-operand

// =================== main: 8-wave blocks, k-parity split -> 4 waves/SIMD ===================
// Every model except "per-wave chain latency at ~2 waves/SIMD" is falsified. This is the
// clean TLP x2 test: 512-thr blocks (8 waves), 512 blocks = 16 waves/CU = 4 waves/SIMD.
// Waves split by k-parity (group0 even tiles, group1 odd) sharing ONE K-ring (each tile
// staged once); V VMEM-direct (R19); per-wave tile structure identical to R17. No memset/
// atomics: k-partials combined via intra-block LDS reduction, group0 stores.
__global__ __launch_bounds__(512, 4) void pa_main(
    const _Float16* __restrict__ KF, const _Float16* __restrict__ VF,
    const unsigned char* __restrict__ PB, const float* __restrict__ q,
    const float* __restrict__ relbias, float* __restrict__ out) {
  __shared__ __align__(16) _Float16 ringK[4][2048];  // 16KB K ring (also reduce scratch)
  __shared__ f32x2 tabF[441];                        // (rb[i], rb[j]) pair table

  const int tid = threadIdx.x, lane = tid & 63, wid = tid >> 6;  // wid 0..7
  const int w4 = wid & 3, par = wid >> 2;                        // chunk, k-parity
  const int l16 = lane & 15, g4 = lane >> 4;
  const int xcd = blockIdx.x & 7;        // bid%8 = XCD
  const int i = blockIdx.x >> 3;         // 0..63 within XCD
  const int b = xcd >> 2;                // XCD owns (b, 4-head group)
  const int hg = xcd & 3;
  const int h = hg * 4 + (i & 3);
  const int qgrp = i >> 2;               // 0..15
  const int qblk = qgrp * 4 + w4;
  const int qbase = qblk * 32;

  // build pair table
  for (int e = tid; e < 441; e += 512) {
    int bi = e / 21, bj = e - bi * 21;
    float vi = (bi < NB) ? relbias[bi * NH + h] : -30000.0f;
    float vj = (bj < NB) ? relbias[bj * NH + h] : -30000.0f;
    tabF[e] = (f32x2){vi, vj};
  }

  half8 qf[2][2];
#pragma unroll
  for (int qs = 0; qs < 2; ++qs)
#pragma unroll
    for (int dh = 0; dh < 2; ++dh) {
      const float* s = q + ((size_t)(b * SEQ + qbase + qs * 16 + l16)) * DM + h * 64 + dh * 32 + g4 * 8;
      f32x4 a = *(const f32x4*)s;
      f32x4 c = *(const f32x4*)(s + 4);
      qf[qs][dh] = {(_Float16)(a[0] * 0.125f), (_Float16)(a[1] * 0.125f),
                    (_Float16)(a[2] * 0.125f), (_Float16)(a[3] * 0.125f),
                    (_Float16)(c[0] * 0.125f), (_Float16)(c[1] * 0.125f),
                    (_Float16)(c[2] * 0.125f), (_Float16)(c[3] * 0.125f)};
    }

  f32x4 acc[2][4];
#pragma unroll
  for (int qs = 0; qs < 2; ++qs)
#pragma unroll
    for (int dt = 0; dt < 4; ++dt) acc[qs][dt] = (f32x4){0.f, 0.f, 0.f, 0.f};

  const _Float16* kfb = KF + ((size_t)((b * 16 + h) * 64)) * 2048 + lane * 8;
  const _Float16* vfb = VF + ((size_t)((b * 16 + h) * 64)) * 2048 + lane * 8;
  const unsigned char* pbb = PB + ((size_t)(b * 64 + qblk)) * 65536 + lane * 16;
  const int c512 = w4 * 512;

  // wave stages chunk w4 of tile T (tiles assigned by caller per parity)
#define STAGE(T) gll16(kfb + (size_t)(T) * 2048 + c512, &ringK[(T) & 3][c512])
#define CLMP(T) ((T) < 64 ? (T) : 63)

#define GATHER(BS, PQ)                                                 \
  do {                                                                 \
    _Pragma("unroll") for (int qs = 0; qs < 2; ++qs)                   \
      _Pragma("unroll") for (int k2 = 0; k2 < 2; ++k2) {               \
        u32 w = (u32)PQ[qs * 2 + k2];                                  \
        f32x2 p01 = tabF[w & 0xffffu];                                 \
        f32x2 p23 = tabF[w >> 16];                                     \
        BS.b[qs][k2] = (f32x4){p01[0], p01[1], p23[0], p23[1]};        \
      }                                                                \
  } while (0)

#define COMPUTE(T, BS)                                                                       \
  do {                                                                                       \
    int sl_ = (T) & 3;                                                                       \
    half8 vvr[4];                                                                            \
    _Pragma("unroll") for (int j = 0; j < 4; ++j)                                            \
      vvr[j] = *(const half8*)(vfb + (size_t)(T) * 2048 + j * 512);   /* VMEM / L1 */        \
    half8 kfr[4];                                                                            \
    _Pragma("unroll") for (int j = 0; j < 4; ++j)                                            \
      kfr[j] = *(const half8*)&ringK[sl_][j * 512 + lane * 8];        /* LDS pipe */         \
    f32x4 sa[2][2];                                                                          \
    _Pragma("unroll") for (int qs = 0; qs < 2; ++qs)                                         \
      _Pragma("unroll") for (int k2 = 0; k2 < 2; ++k2) {                                     \
        sa[qs][k2] = __builtin_amdgcn_mfma_f32_16x16x32_f16(kfr[k2 * 2 + 0], qf[qs][0],      \
                                                            BS.b[qs][k2], 0, 0, 0);          \
        sa[qs][k2] = __builtin_amdgcn_mfma_f32_16x16x32_f16(kfr[k2 * 2 + 1], qf[qs][1],      \
                                                            sa[qs][k2], 0, 0, 0);            \
      }                                                                                      \
    half8 pf8[2];                                                                            \
    _Pragma("unroll") for (int qs = 0; qs < 2; ++qs) {                                       \
      half4 p0 = silu4nb(sa[qs][0]);                                                         \
      half4 p1 = silu4nb(sa[qs][1]);                                                         \
      pf8[qs] = (half8){p0[0], p0[1], p0[2], p0[3], p1[0], p1[1], p1[2], p1[3]};             \
    }                                                                                        \
    _Pragma("unroll") for (int qs = 0; qs < 2; ++qs)                                         \
      _Pragma("unroll") for (int dt = 0; dt < 4; ++dt)                                       \
        acc[qs][dt] = __builtin_amdgcn_mfma_f32_16x16x32_f16(pf8[qs], vvr[dt],               \
                                                             acc[qs][dt], 0, 0, 0);          \
  } while (0)

  BiasSet bias;
  i32x4 pqCur, pqNext;

  // prologue: stage tiles 0..3 (wave stages chunk w4 of tiles par, par+2); pq(par) in flight
  STAGE(par);
  STAGE(par + 2);
  pqCur = *(const i32x4*)(pbb + (size_t)par * 1024);
  __syncthreads();                       // stages 0..3 complete (barrier drains vmcnt)

  for (int p = 0; p < 32; ++p) {
    const int T = 2 * p + par;           // this wave's tile
    // stage tile T+4's chunk (slot (T+4)&3 = T&3 of the OTHER parity's past — disjoint
    // from both computed slots T&3,(T^1)&3? (T+4)&3 == T&3: same slot as computing!
    // -> stage T+4 AFTER compute would race next phase. Instead stage 2 ahead per parity:
    // phase p stages tile 2p+4+par (slot (2p+4+par)&3 = (2p+par)&3 ... same issue).
    // Resolution (R17 discipline): stage happens HERE for tile 2(p+2)+par? No —
    // correct safe pattern: stage tiles 2p+4,2p+5 would collide. Use compute-then-stage
    // with barrier BETWEEN: compute T (slot T&3), barrier, stage T+4 (slot T&3, now free).
    pqNext = *(const i32x4*)(pbb + (size_t)CLMP(T + 2) * 1024);
    __builtin_amdgcn_sched_barrier(0);
    GATHER(bias, pqCur);
    COMPUTE(T, bias);
    __syncthreads();                     // all waves done reading slots 2p&3,(2p+1)&3
    if (T + 4 < 64) STAGE(T + 4);        // refill freed slot (T+4)&3 == T&3
    pqCur = pqNext;
    __syncthreads();                     // stages for tiles 2p+4,2p+5 complete before use
  }
#undef STAGE
#undef CLMP
#undef GATHER
#undef COMPUTE

  // epilogue: combine k-parity partials via LDS (2 rounds of 16KB), group0 stores
  f32x4* red = (f32x4*)ringK;
#pragma unroll
  for (int qs = 0; qs < 2; ++qs) {
    __syncthreads();
    if (par == 1) {
#pragma unroll
      for (int dt = 0; dt < 4; ++dt) red[(w4 * 64 + lane) * 4 + dt] = acc[qs][dt];
    }
    __syncthreads();
    if (par == 0) {
#pragma unroll
      for (int dt = 0; dt < 4; ++dt) {
        f32x4 sum = acc[qs][dt] + red[(w4 * 64 + lane) * 4 + dt];
#pragma unroll
        for (int r = 0; r < 4; ++r) {
          int qrow = qbase + qs * 16 + g4 * 4 + r;
          int d = h * 64 + dt * 16 + l16;
          out[((size_t)(b * SEQ) + qrow) * DM + d] = sum[r];
        }
      }
    }
  }
}

extern "C" void kernel_launch(void* const* d_in, const int* in_sizes, int n_in,
                              void* d_out, int out_size, void* d_ws, size_t ws_size,
                              hipStream_t stream) {
  const float* v = (const float*)d_in[0];
  const float* k = (const float*)d_in[1];
  const float* q = (const float*)d_in[2];
  const int* mask = (const int*)d_in[3];
  const int* diff = (const int*)d_in[4];
  const float* relbias = (const float*)d_in[5];
  float* out = (float*)d_out;

  _Float16* KF = (_Float16*)d_ws;
  _Float16* VF = KF + KF_HALVES;
  unsigned char* PB = (unsigned char*)(VF + VF_HALVES);
  if (ws_size < (size_t)25165824) return;

  pa_prep<<<7168, 256, 0, stream>>>(v, k, diff, mask, KF, VF, PB);
  pa_main<<<512, 512, 0, stream>>>(KF, VF, PB, q, relbias, out);
}